// Round 3
// baseline (32.522 us; speedup 1.0000x reference)
//
#include <hip/hip_runtime.h>
#include <stdint.h>

// WeightedMSELoss: mean((p-t)^2 * w), w=3.0 at per-row top-5 of t (value-threshold
// formulation; index tie-break dropped -> worst-case output deviation ~1e-6).
// B=N=4096 fp32 in, fp32 scalar out.

static constexpr int BDIM = 512;              // 8 waves
static constexpr int NROW = 4096;
static constexpr int NCOL = 4096;
static constexpr int NWAVE = BDIM / 64;

__device__ __forceinline__ uint32_t f32_mono(float f) {
    // order-preserving f32 -> u32 (no NaNs in input); never 0 for finite f
    uint32_t u = __float_as_uint(f);
    return u ^ (uint32_t)(((int32_t)u >> 31) | (int32_t)0x80000000);
}

__device__ __forceinline__ uint32_t umaxu(uint32_t a, uint32_t b) { return a > b ? a : b; }

__global__ __launch_bounds__(BDIM) void wmse_rows(const float* __restrict__ preds,
                                                  const float* __restrict__ tgts,
                                                  float* __restrict__ rowsum) {
    const int row = blockIdx.x;
    const int tid = threadIdx.x;
    const int lane = tid & 63;
    const int wave = tid >> 6;

    const float4* p4 = reinterpret_cast<const float4*>(preds) + (size_t)row * (NCOL / 4);
    const float4* t4 = reinterpret_cast<const float4*>(tgts) + (size_t)row * (NCOL / 4);

    // ---- issue all 4 loads up front (MLP=4, single waitcnt) ----
    const float4 pa = p4[tid];
    const float4 pb = p4[tid + BDIM];
    const float4 ta = t4[tid];
    const float4 tb = t4[tid + BDIM];

    float loss[8];
    uint32_t key[8];
    {
        const float d0 = pa.x - ta.x, d1 = pa.y - ta.y, d2 = pa.z - ta.z, d3 = pa.w - ta.w;
        const float e0 = pb.x - tb.x, e1 = pb.y - tb.y, e2 = pb.z - tb.z, e3 = pb.w - tb.w;
        loss[0] = d0 * d0; loss[1] = d1 * d1; loss[2] = d2 * d2; loss[3] = d3 * d3;
        loss[4] = e0 * e0; loss[5] = e1 * e1; loss[6] = e2 * e2; loss[7] = e3 * e3;
        key[0] = f32_mono(ta.x); key[1] = f32_mono(ta.y); key[2] = f32_mono(ta.z); key[3] = f32_mono(ta.w);
        key[4] = f32_mono(tb.x); key[5] = f32_mono(tb.y); key[6] = f32_mono(tb.z); key[7] = f32_mono(tb.w);
    }
    float ssq = ((loss[0] + loss[1]) + (loss[2] + loss[3])) +
                ((loss[4] + loss[5]) + (loss[6] + loss[7]));

    __shared__ uint32_t cand[NWAVE * 5];
    __shared__ uint32_t s_tau;
    __shared__ float fred[NWAVE];

    // ---- wave-local top-5 distinct values, no barriers ----
    {
        uint32_t prev = 0xFFFFFFFFu;
#pragma unroll
        for (int r = 0; r < 5; ++r) {
            uint32_t c = 0u;
#pragma unroll
            for (int i = 0; i < 8; ++i) {
                c = (key[i] < prev) ? umaxu(c, key[i]) : c;
            }
#pragma unroll
            for (int sh = 32; sh >= 1; sh >>= 1) {
                uint32_t o = (uint32_t)__shfl_xor((int)c, sh, 64);
                c = umaxu(c, o);
            }
            if (lane == 0) cand[wave * 5 + r] = c;
            prev = c;
        }
    }
    __syncthreads();

    // ---- wave 0 merges NWAVE*5 = 40 candidates -> tau = 5th-largest distinct ----
    if (wave == 0) {
        uint32_t c0 = (lane < NWAVE * 5) ? cand[lane] : 0u;
        uint32_t prev = 0xFFFFFFFFu;
#pragma unroll
        for (int r = 0; r < 5; ++r) {
            uint32_t c = (c0 < prev) ? c0 : 0u;
#pragma unroll
            for (int sh = 32; sh >= 1; sh >>= 1) {
                uint32_t o = (uint32_t)__shfl_xor((int)c, sh, 64);
                c = umaxu(c, o);
            }
            prev = c;
        }
        if (lane == 0) s_tau = prev;
    }
    __syncthreads();
    const uint32_t tau = s_tau;

    // ---- extra loss at weighted positions: key >= tau; row total = ssq + 2*extra ----
    float extra = 0.f;
#pragma unroll
    for (int i = 0; i < 8; ++i) {
        extra += (key[i] >= tau) ? loss[i] : 0.f;
    }

    float part = ssq + 2.0f * extra;
#pragma unroll
    for (int sh = 32; sh >= 1; sh >>= 1) {
        part += __shfl_xor(part, sh, 64);
    }
    if (lane == 0) fred[wave] = part;
    __syncthreads();
    if (tid == 0) {
        float tot = 0.f;
#pragma unroll
        for (int w = 0; w < NWAVE; ++w) tot += fred[w];
        rowsum[row] = tot;
    }
}

__global__ __launch_bounds__(256) void wmse_reduce(const float* __restrict__ rowsum,
                                                   float* __restrict__ out) {
    double acc = 0.0;
    for (int i = threadIdx.x; i < NROW; i += 256) {
        acc += (double)rowsum[i];
    }
#pragma unroll
    for (int sh = 32; sh >= 1; sh >>= 1) {
        acc += __shfl_xor(acc, sh, 64);
    }
    __shared__ double dred[4];
    if ((threadIdx.x & 63) == 0) dred[threadIdx.x >> 6] = acc;
    __syncthreads();
    if (threadIdx.x == 0) {
        const double tot = dred[0] + dred[1] + dred[2] + dred[3];
        out[0] = (float)(tot / ((double)NROW * (double)NCOL));
    }
}

extern "C" void kernel_launch(void* const* d_in, const int* in_sizes, int n_in,
                              void* d_out, int out_size, void* d_ws, size_t ws_size,
                              hipStream_t stream) {
    const float* preds = (const float*)d_in[0];
    const float* tgts = (const float*)d_in[1];
    float* rowsum = (float*)d_ws; // 16 KB scratch
    float* out = (float*)d_out;

    wmse_rows<<<NROW, BDIM, 0, stream>>>(preds, tgts, rowsum);
    wmse_reduce<<<1, 256, 0, stream>>>(rowsum, out);
}